// Round 5
// baseline (8384.088 us; speedup 1.0000x reference)
//
#include <hip/hip_runtime.h>
#include <stdint.h>

// MD-GRU 2D, 4 directions. B=32, IN=64, H=W=64 (63x63 cells), HID=128.
// Persistent wavefront pipeline (one 512-thread WG per direction*column),
// flag+fence h_left handoff. Per-cell GEMM done on matrix cores via
// split-bf16 (hi+lo) 3-product fp32 emulation with mfma_f32_16x16x32_bf16.

#define NB   32
#define NIN  64
#define NHID 128
#define NG   384
#define NC   63
#define IMG  64
#define NK   320           // 64 x | 128 h_up | 128 h_left
#define ASTR 328           // LDS A-plane row stride (ushorts), +8 pad
#define GSTR 385           // LDS G-plane row stride (floats), +1 pad
#define OUTB ((size_t)NHID * 4 * IMG * IMG)   // batch stride in out

typedef __attribute__((ext_vector_type(8))) short short8;
typedef __attribute__((ext_vector_type(4))) float fv4;
typedef __attribute__((ext_vector_type(4))) unsigned short us4;

__device__ __forceinline__ float sigmoidf_(float x) { return 1.0f / (1.0f + __expf(-x)); }
__device__ __forceinline__ float tanhf_(float x)    { return 1.0f - 2.0f / (__expf(2.0f * x) + 1.0f); }

__device__ __forceinline__ unsigned short bf16_rne(float f) {
    unsigned int u = __builtin_bit_cast(unsigned int, f);
    u += 0x7fffu + ((u >> 16) & 1u);
    return (unsigned short)(u >> 16);
}
__device__ __forceinline__ float bf16_f(unsigned short h) {
    return __builtin_bit_cast(float, ((unsigned int)h) << 16);
}
__device__ __forceinline__ void split2(float f, unsigned short& hi, unsigned short& lo) {
    hi = bf16_rne(f);
    lo = bf16_rne(f - bf16_f(hi));
}

// x (B,IN,64,64) -> hi/lo bf16 planes xThi/xTlo[(y*63+xc)*2048 + b*64 + i]
__global__ void xsplit_kernel(const float* __restrict__ x,
                              unsigned short* __restrict__ xhi,
                              unsigned short* __restrict__ xlo) {
    int idx = blockIdx.x * 256 + threadIdx.x;
    if (idx >= NC * NC * NB * NIN) return;
    int i  = idx & 63;
    int t1 = idx >> 6;
    int b  = t1 & 31;
    int t2 = t1 >> 5;
    int xc = t2 % NC;
    int y  = t2 / NC;
    float v = x[((size_t)(b * NIN + i) * IMG + y) * IMG + xc];
    unsigned short hi, lo; split2(v, hi, lo);
    xhi[idx] = hi; xlo[idx] = lo;
}

// [Wx;Wh;Wh2] -> K-major hi/lo planes W*[d][gate][k], k = 0..319
__global__ void wsplit_kernel(const float* __restrict__ Wx, const float* __restrict__ Wh,
                              const float* __restrict__ Wh2,
                              unsigned short* __restrict__ whi,
                              unsigned short* __restrict__ wlo) {
    int idx = blockIdx.x * 256 + threadIdx.x;
    if (idx >= 4 * NG * NK) return;
    int k = idx % NK;
    int g = (idx / NK) % NG;
    int d = idx / (NK * NG);
    float v;
    if (k < NIN)             v = Wx [((size_t)d * NIN  + k)                * NG + g];
    else if (k < NIN + NHID) v = Wh [((size_t)d * NHID + (k - NIN))        * NG + g];
    else                     v = Wh2[((size_t)d * NHID + (k - NIN - NHID)) * NG + g];
    unsigned short hi, lo; split2(v, hi, lo);
    whi[idx] = hi; wlo[idx] = lo;
}

// 1.0 border cells of each direction's map. out[b][j][d][Y][X].
__global__ void fill_kernel(float* __restrict__ out) {
    int idx  = blockIdx.x * 256 + threadIdx.x;
    int pos  = idx & 63;
    int line = (idx >> 6) & 1;
    int rest = idx >> 7;
    if (rest >= NB * NHID * 4) return;
    int d  = rest & 3;
    int fy = d & 1, fx = (d >> 1) & 1;
    int Y = line ? pos : (fy ? 0 : 63);
    int X = line ? (fx ? 0 : 63) : pos;
    out[(size_t)rest * (IMG * IMG) + Y * IMG + X] = 1.0f;
}

// One K=32 MFMA step for both M-tiles and this wave's 3 N-tiles into ACC.
// Split products: Ahi*Bhi + Ahi*Blo + Alo*Bhi (Alo*Blo ~2^-18, dropped).
#define KSTEP(S, ACC)                                                                 \
    do {                                                                              \
        short8 a0h = *(const short8*)&As_hi[aoff + (S) * 32];                         \
        short8 a0l = *(const short8*)&As_lo[aoff + (S) * 32];                         \
        short8 a1h = *(const short8*)&As_hi[aoff + 16 * ASTR + (S) * 32];             \
        short8 a1l = *(const short8*)&As_lo[aoff + 16 * ASTR + (S) * 32];             \
        _Pragma("unroll")                                                             \
        for (int t = 0; t < 3; ++t) {                                                 \
            short8 bh = *(const short8*)&wbh[(size_t)t * 16 * NK + (S) * 32];         \
            short8 bl = *(const short8*)&wbl[(size_t)t * 16 * NK + (S) * 32];         \
            ACC[0][t] = __builtin_amdgcn_mfma_f32_16x16x32_bf16(a0h, bh, ACC[0][t], 0, 0, 0); \
            ACC[0][t] = __builtin_amdgcn_mfma_f32_16x16x32_bf16(a0h, bl, ACC[0][t], 0, 0, 0); \
            ACC[0][t] = __builtin_amdgcn_mfma_f32_16x16x32_bf16(a0l, bh, ACC[0][t], 0, 0, 0); \
            ACC[1][t] = __builtin_amdgcn_mfma_f32_16x16x32_bf16(a1h, bh, ACC[1][t], 0, 0, 0); \
            ACC[1][t] = __builtin_amdgcn_mfma_f32_16x16x32_bf16(a1h, bl, ACC[1][t], 0, 0, 0); \
            ACC[1][t] = __builtin_amdgcn_mfma_f32_16x16x32_bf16(a1l, bh, ACC[1][t], 0, 0, 0); \
        }                                                                             \
    } while (0)

__global__ __launch_bounds__(512) void mdgru_kernel(
    const unsigned short* __restrict__ xhi, const unsigned short* __restrict__ xlo,
    const float* __restrict__ xraw, int use_xt,
    const unsigned short* __restrict__ Whi, const unsigned short* __restrict__ Wlo,
    const float* __restrict__ bias,
    float* __restrict__ out, unsigned int* __restrict__ stage, int use_stage,
    int* flags)
{
    extern __shared__ char smem[];
    unsigned short* As_hi = (unsigned short*)smem;               // 32*328*2 = 20992 B
    unsigned short* As_lo = (unsigned short*)(smem + 20992);     // 20992 B
    float*          Gx    = (float*)(smem + 41984);              // 32*385*4 = 49280 B
    float*          Gh    = (float*)(smem + 91264);              // 49280 B  (total 140544)

    const int blk = blockIdx.x;
    const int d   = blk / NC;
    const int c   = blk - d * NC;
    const int fy  = d & 1;
    const int fx  = (d >> 1) & 1;
    const int tid  = threadIdx.x;
    const int lane = tid & 63;
    const int wid  = tid >> 6;          // 0..7
    const int l15  = lane & 15;
    const int l4   = lane >> 4;
    const int j    = tid & (NHID - 1);  // epilogue hidden index
    const int bsub = tid >> 7;          // 0..3
    const int b0   = bsub * 8;

    const int xi = fx ? (62 - c) : c;
    const int X  = fx ? (63 - c) : c;
    const int Xp = fx ? (63 - (c - 1)) : (c - 1);

    // MFMA fragment lane offsets (A: row=l15, k=l4*8+i ; B: col=l15, k=l4*8+i)
    const int aoff = l15 * ASTR + l4 * 8;
    const unsigned short* wbh = Whi + ((size_t)d * NG + wid * 48 + l15) * NK + l4 * 8;
    const unsigned short* wbl = Wlo + ((size_t)d * NG + wid * 48 + l15) * NK + l4 * 8;

    const float bR = bias[d * NG + j];
    const float bZ = bias[d * NG + NHID + j];
    const float bN = bias[d * NG + 2 * NHID + j];

    // ---- prologue: zero h_up/h_left sections of both A planes; stage x row 0
    for (int e = tid; e < NB * 256; e += 512) {
        int bb = e >> 8, kk = e & 255;
        As_hi[bb * ASTR + 64 + kk] = 0;
        As_lo[bb * ASTR + 64 + kk] = 0;
    }
    {
        const int yi0 = fy ? 62 : 0;
        if (use_xt) {
            const size_t src = (size_t)(yi0 * NC + xi) * (NB * NIN) + tid * 4;
            us4 vh = *(const us4*)&xhi[src];
            us4 vl = *(const us4*)&xlo[src];
            const int e = tid * 4, bb = e >> 6, ii = e & 63;
            *(us4*)&As_hi[bb * ASTR + ii] = vh;
            *(us4*)&As_lo[bb * ASTR + ii] = vl;
        } else {
            for (int e = tid; e < NB * NIN; e += 512) {
                int bb = e >> 6, ii = e & 63;
                float v = xraw[((size_t)(bb * NIN + ii) * IMG + yi0) * IMG + xi];
                unsigned short hi, lo; split2(v, hi, lo);
                As_hi[bb * ASTR + ii] = hi;
                As_lo[bb * ASTR + ii] = lo;
            }
        }
    }
    float hprev[8];
#pragma unroll
    for (int q = 0; q < 8; ++q) hprev[q] = 0.0f;

    for (int r = 0; r < NC; ++r) {
        const int Y = fy ? (63 - r) : r;
        __syncthreads();                               // B1: As for row r ready

        fv4 accX[2][3], accH[2][3];
#pragma unroll
        for (int m = 0; m < 2; ++m)
#pragma unroll
            for (int t = 0; t < 3; ++t) {
                accX[m][t] = (fv4){0.f, 0.f, 0.f, 0.f};
                accH[m][t] = (fv4){0.f, 0.f, 0.f, 0.f};
            }

        // x part (k 0..63) -> accX ; prefetch next row's x
        KSTEP(0, accX); KSTEP(1, accX);
        us4 pxh, pxl; int have_px = 0;
        if (use_xt) {
            const int rn  = (r + 1 < NC) ? r + 1 : NC - 1;
            const int yin = fy ? (62 - rn) : rn;
            const size_t src = (size_t)(yin * NC + xi) * (NB * NIN) + tid * 4;
            pxh = *(const us4*)&xhi[src];
            pxl = *(const us4*)&xlo[src];
            have_px = 1;
        }
        // h_up part (k 64..191) -> accH
        KSTEP(2, accH); KSTEP(3, accH); KSTEP(4, accH); KSTEP(5, accH);

        // ---- acquire h_left from (d, c-1) row r ----
        float hl[8];
        if (c > 0) {
            if (tid == 0) {
                const int fidx = (d * NC + (c - 1)) * NC + r;
                int cnt = 0;
                while (__hip_atomic_load(&flags[fidx], __ATOMIC_RELAXED,
                                         __HIP_MEMORY_SCOPE_AGENT) == 0) {
                    __builtin_amdgcn_s_sleep(2);
                    if (++cnt > (1 << 22)) break;       // safety valve
                }
            }
            __syncthreads();                            // B2
            __builtin_amdgcn_fence(__ATOMIC_ACQUIRE, "agent");
            if (use_stage) {
                const unsigned int* sp = stage +
                    ((size_t)(d * 2 + ((c - 1) & 1)) * NC + r) * (NB * NHID);
#pragma unroll
                for (int q = 0; q < 8; ++q) {
                    unsigned int p = __hip_atomic_load(sp + (b0 + q) * NHID + j,
                                                       __ATOMIC_RELAXED, __HIP_MEMORY_SCOPE_AGENT);
                    unsigned short hi = (unsigned short)(p >> 16);
                    unsigned short lo = (unsigned short)(p & 0xffffu);
                    hl[q] = bf16_f(hi) + bf16_f(lo);
                    As_hi[(b0 + q) * ASTR + 192 + j] = hi;
                    As_lo[(b0 + q) * ASTR + 192 + j] = lo;
                }
            } else {
                const float* pb = out + (size_t)j * (4 * IMG * IMG) + d * (IMG * IMG)
                                 + Y * IMG + Xp + (size_t)b0 * OUTB;
#pragma unroll
                for (int q = 0; q < 8; ++q) {
                    float v = __hip_atomic_load(pb + (size_t)q * OUTB,
                                                __ATOMIC_RELAXED, __HIP_MEMORY_SCOPE_AGENT);
                    hl[q] = v;
                    unsigned short hi, lo; split2(v, hi, lo);
                    As_hi[(b0 + q) * ASTR + 192 + j] = hi;
                    As_lo[(b0 + q) * ASTR + 192 + j] = lo;
                }
            }
            __syncthreads();                            // B3: h_left in LDS
        } else {
#pragma unroll
            for (int q = 0; q < 8; ++q) hl[q] = 0.0f;   // As h_left stays zero
        }

        // h_left part (k 192..319) -> accH
        KSTEP(6, accH); KSTEP(7, accH); KSTEP(8, accH); KSTEP(9, accH);

        // ---- regroup gates across waves via LDS ----
#pragma unroll
        for (int m = 0; m < 2; ++m)
#pragma unroll
            for (int t = 0; t < 3; ++t)
#pragma unroll
                for (int v = 0; v < 4; ++v) {
                    const int row = m * 16 + l4 * 4 + v;
                    const int g   = wid * 48 + t * 16 + l15;
                    Gx[row * GSTR + g] = accX[m][t][v];
                    Gh[row * GSTR + g] = accH[m][t][v];
                }
        __syncthreads();                                // B4: G ready

        // ---- gates + combine (fp32, exact reference form) ----
        unsigned int pu[8];
        unsigned short hhi[8], hlo[8];
#pragma unroll
        for (int q = 0; q < 8; ++q) {
            const int b = b0 + q;
            float gr = bR + Gx[b * GSTR + j]            + Gh[b * GSTR + j];
            float gz = bZ + Gx[b * GSTR + NHID + j]     + Gh[b * GSTR + NHID + j];
            float nx = bN + Gx[b * GSTR + 2 * NHID + j];
            float nh =      Gh[b * GSTR + 2 * NHID + j];
            float rg = sigmoidf_(gr);
            float zg = sigmoidf_(gz);
            float ng = tanhf_(fmaf(rg, nh, nx));
            float h  = (1.0f - zg) * ng + zg * 0.5f * (hprev[q] + hl[q]);
            hprev[q] = h;
            split2(h, hhi[q], hlo[q]);
            pu[q] = ((unsigned int)hhi[q] << 16) | hlo[q];
        }

        // ---- publish ----
        float* ob = out + (size_t)j * (4 * IMG * IMG) + d * (IMG * IMG)
                   + Y * IMG + X + (size_t)b0 * OUTB;
        if (use_stage) {
            if (c < NC - 1) {
                unsigned int* sw = stage +
                    ((size_t)(d * 2 + (c & 1)) * NC + r) * (NB * NHID) + b0 * NHID + j;
#pragma unroll
                for (int q = 0; q < 8; ++q)
                    __hip_atomic_store(sw + q * NHID, pu[q], __ATOMIC_RELAXED,
                                       __HIP_MEMORY_SCOPE_AGENT);
                __builtin_amdgcn_fence(__ATOMIC_RELEASE, "agent");
            }
            __syncthreads();                            // B5
            if (c < NC - 1 && tid == 0)
                __hip_atomic_store(&flags[(d * NC + c) * NC + r], 1,
                                   __ATOMIC_RELEASE, __HIP_MEMORY_SCOPE_AGENT);
#pragma unroll
            for (int q = 0; q < 8; ++q)
                ob[(size_t)q * OUTB] = hprev[q];        // off critical chain
        } else {
            // out IS the handoff surface
#pragma unroll
            for (int q = 0; q < 8; ++q)
                __hip_atomic_store(ob + (size_t)q * OUTB, hprev[q],
                                   __ATOMIC_RELAXED, __HIP_MEMORY_SCOPE_AGENT);
            if (c < NC - 1) __builtin_amdgcn_fence(__ATOMIC_RELEASE, "agent");
            __syncthreads();                            // B5
            if (c < NC - 1 && tid == 0)
                __hip_atomic_store(&flags[(d * NC + c) * NC + r], 1,
                                   __ATOMIC_RELEASE, __HIP_MEMORY_SCOPE_AGENT);
        }

        // ---- write next row's As: h_up (from h) + x (prefetched) ----
#pragma unroll
        for (int q = 0; q < 8; ++q) {
            As_hi[(b0 + q) * ASTR + 64 + j] = hhi[q];
            As_lo[(b0 + q) * ASTR + 64 + j] = hlo[q];
        }
        if (have_px) {
            const int e = tid * 4, bb = e >> 6, ii = e & 63;
            *(us4*)&As_hi[bb * ASTR + ii] = pxh;
            *(us4*)&As_lo[bb * ASTR + ii] = pxl;
        } else if (r + 1 < NC) {
            const int yin = fy ? (62 - (r + 1)) : (r + 1);
            for (int e = tid; e < NB * NIN; e += 512) {
                int bb = e >> 6, ii = e & 63;
                float v = xraw[((size_t)(bb * NIN + ii) * IMG + yin) * IMG + xi];
                unsigned short hi, lo; split2(v, hi, lo);
                As_hi[bb * ASTR + ii] = hi;
                As_lo[bb * ASTR + ii] = lo;
            }
        }
    }
}

extern "C" void kernel_launch(void* const* d_in, const int* in_sizes, int n_in,
                              void* d_out, int out_size, void* d_ws, size_t ws_size,
                              hipStream_t stream) {
    const float* x    = (const float*)d_in[0];
    const float* Wx   = (const float*)d_in[1];
    const float* Wh   = (const float*)d_in[2];
    const float* Wh2  = (const float*)d_in[3];
    const float* bias = (const float*)d_in[4];
    float* out = (float*)d_out;

    // workspace layout
    const size_t FLAGS_BYTES = 65536;
    const size_t WHI_OFF  = FLAGS_BYTES;                        // 983,040
    const size_t WSZ      = (size_t)4 * NG * NK * 2;
    const size_t WLO_OFF  = WHI_OFF + WSZ;
    const size_t XHI_OFF  = WLO_OFF + WSZ;                      // 16,257,024 each
    const size_t XSZ      = (size_t)NC * NC * NB * NIN * 2;
    const size_t XLO_OFF  = XHI_OFF + XSZ;
    const size_t STG_OFF  = XLO_OFF + XSZ;                      // parity-ring stage
    const size_t STG_SZ   = (size_t)4 * 2 * NC * NB * NHID * 4; // 8,257,536
    const size_t SMEM     = 140544;

    int*            flags = (int*)d_ws;
    unsigned short* whi   = (unsigned short*)((char*)d_ws + WHI_OFF);
    unsigned short* wlo   = (unsigned short*)((char*)d_ws + WLO_OFF);
    unsigned short* xhi   = (unsigned short*)((char*)d_ws + XHI_OFF);
    unsigned short* xlo   = (unsigned short*)((char*)d_ws + XLO_OFF);
    unsigned int*   stage = (unsigned int*)((char*)d_ws + STG_OFF);
    const int use_xt    = ws_size >= XLO_OFF + XSZ;
    const int use_stage = ws_size >= STG_OFF + STG_SZ;

    (void)hipFuncSetAttribute((const void*)mdgru_kernel,
                              hipFuncAttributeMaxDynamicSharedMemorySize, (int)SMEM);

    size_t mset = ws_size < FLAGS_BYTES ? ws_size : FLAGS_BYTES;
    hipMemsetAsync(d_ws, 0, mset, stream);               // flags start at 0

    {
        const int total = 4 * NG * NK;
        wsplit_kernel<<<(total + 255) / 256, 256, 0, stream>>>(Wx, Wh, Wh2, whi, wlo);
    }
    if (use_xt) {
        const int total = NC * NC * NB * NIN;
        xsplit_kernel<<<(total + 255) / 256, 256, 0, stream>>>(x, xhi, xlo);
    }
    fill_kernel<<<(NB * NHID * 4 * 2 * 64 + 255) / 256, 256, 0, stream>>>(out);
    mdgru_kernel<<<4 * NC, 512, SMEM, stream>>>(xhi, xlo, x, use_xt, whi, wlo, bias,
                                                out, stage, use_stage, flags);
}

// Round 6
// 5606.717 us; speedup vs baseline: 1.4954x; 1.4954x over previous
//
#include <hip/hip_runtime.h>
#include <stdint.h>

// MD-GRU 2D, 4 directions. B=32, IN=64, H=W=64 (63x63 cells), HID=128.
// Persistent wavefront pipeline (one 512-thread WG per direction*column),
// flag h_left handoff via agent-scope (sc0/sc1, L2-bypassing) atomics.
// NO agent fences in the loop: they emit buffer_wbl2/buffer_inv on gfx950,
// which invalidated the XCD L2 every cell and caused 2.9 GB of weight
// re-fetch per dispatch (round-5 counters). Ordering = s_waitcnt vmcnt(0)
// before the flag store; consumer orders via post-poll __syncthreads.
// Per-cell GEMM on matrix cores via split-bf16 (hi+lo) 3-product emulation.

#define NB   32
#define NIN  64
#define NHID 128
#define NG   384
#define NC   63
#define IMG  64
#define NK   320           // 64 x | 128 h_up | 128 h_left
#define ASTR 328           // LDS A-plane row stride (ushorts), +8 pad
#define GSTR 385           // LDS G-plane row stride (floats), +1 pad
#define OUTB ((size_t)NHID * 4 * IMG * IMG)   // batch stride in out

typedef __attribute__((ext_vector_type(8))) short short8;
typedef __attribute__((ext_vector_type(4))) float fv4;
typedef __attribute__((ext_vector_type(4))) unsigned short us4;

__device__ __forceinline__ float sigmoidf_(float x) { return 1.0f / (1.0f + __expf(-x)); }
__device__ __forceinline__ float tanhf_(float x)    { return 1.0f - 2.0f / (__expf(2.0f * x) + 1.0f); }

__device__ __forceinline__ unsigned short bf16_rne(float f) {
    unsigned int u = __builtin_bit_cast(unsigned int, f);
    u += 0x7fffu + ((u >> 16) & 1u);
    return (unsigned short)(u >> 16);
}
__device__ __forceinline__ float bf16_f(unsigned short h) {
    return __builtin_bit_cast(float, ((unsigned int)h) << 16);
}
__device__ __forceinline__ void split2(float f, unsigned short& hi, unsigned short& lo) {
    hi = bf16_rne(f);
    lo = bf16_rne(f - bf16_f(hi));
}

// x (B,IN,64,64) -> hi/lo bf16 planes xThi/xTlo[(y*63+xc)*2048 + b*64 + i]
__global__ void xsplit_kernel(const float* __restrict__ x,
                              unsigned short* __restrict__ xhi,
                              unsigned short* __restrict__ xlo) {
    int idx = blockIdx.x * 256 + threadIdx.x;
    if (idx >= NC * NC * NB * NIN) return;
    int i  = idx & 63;
    int t1 = idx >> 6;
    int b  = t1 & 31;
    int t2 = t1 >> 5;
    int xc = t2 % NC;
    int y  = t2 / NC;
    float v = x[((size_t)(b * NIN + i) * IMG + y) * IMG + xc];
    unsigned short hi, lo; split2(v, hi, lo);
    xhi[idx] = hi; xlo[idx] = lo;
}

// [Wx;Wh;Wh2] -> K-major hi/lo planes W*[d][gate][k], k = 0..319
__global__ void wsplit_kernel(const float* __restrict__ Wx, const float* __restrict__ Wh,
                              const float* __restrict__ Wh2,
                              unsigned short* __restrict__ whi,
                              unsigned short* __restrict__ wlo) {
    int idx = blockIdx.x * 256 + threadIdx.x;
    if (idx >= 4 * NG * NK) return;
    int k = idx % NK;
    int g = (idx / NK) % NG;
    int d = idx / (NK * NG);
    float v;
    if (k < NIN)             v = Wx [((size_t)d * NIN  + k)                * NG + g];
    else if (k < NIN + NHID) v = Wh [((size_t)d * NHID + (k - NIN))        * NG + g];
    else                     v = Wh2[((size_t)d * NHID + (k - NIN - NHID)) * NG + g];
    unsigned short hi, lo; split2(v, hi, lo);
    whi[idx] = hi; wlo[idx] = lo;
}

// 1.0 border cells of each direction's map. out[b][j][d][Y][X].
__global__ void fill_kernel(float* __restrict__ out) {
    int idx  = blockIdx.x * 256 + threadIdx.x;
    int pos  = idx & 63;
    int line = (idx >> 6) & 1;
    int rest = idx >> 7;
    if (rest >= NB * NHID * 4) return;
    int d  = rest & 3;
    int fy = d & 1, fx = (d >> 1) & 1;
    int Y = line ? pos : (fy ? 0 : 63);
    int X = line ? (fx ? 0 : 63) : pos;
    out[(size_t)rest * (IMG * IMG) + Y * IMG + X] = 1.0f;
}

// One K=32 MFMA step for both M-tiles and this wave's 3 N-tiles into ACC.
// Split products: Ahi*Bhi + Ahi*Blo + Alo*Bhi (Alo*Blo ~2^-18, dropped).
#define KSTEP(S, ACC)                                                                 \
    do {                                                                              \
        short8 a0h = *(const short8*)&As_hi[aoff + (S) * 32];                         \
        short8 a0l = *(const short8*)&As_lo[aoff + (S) * 32];                         \
        short8 a1h = *(const short8*)&As_hi[aoff + 16 * ASTR + (S) * 32];             \
        short8 a1l = *(const short8*)&As_lo[aoff + 16 * ASTR + (S) * 32];             \
        _Pragma("unroll")                                                             \
        for (int t = 0; t < 3; ++t) {                                                 \
            short8 bh = *(const short8*)&wbh[(size_t)t * 16 * NK + (S) * 32];         \
            short8 bl = *(const short8*)&wbl[(size_t)t * 16 * NK + (S) * 32];         \
            ACC[0][t] = __builtin_amdgcn_mfma_f32_16x16x32_bf16(a0h, bh, ACC[0][t], 0, 0, 0); \
            ACC[0][t] = __builtin_amdgcn_mfma_f32_16x16x32_bf16(a0h, bl, ACC[0][t], 0, 0, 0); \
            ACC[0][t] = __builtin_amdgcn_mfma_f32_16x16x32_bf16(a0l, bh, ACC[0][t], 0, 0, 0); \
            ACC[1][t] = __builtin_amdgcn_mfma_f32_16x16x32_bf16(a1h, bh, ACC[1][t], 0, 0, 0); \
            ACC[1][t] = __builtin_amdgcn_mfma_f32_16x16x32_bf16(a1h, bl, ACC[1][t], 0, 0, 0); \
            ACC[1][t] = __builtin_amdgcn_mfma_f32_16x16x32_bf16(a1l, bh, ACC[1][t], 0, 0, 0); \
        }                                                                             \
    } while (0)

__global__ __launch_bounds__(512) void mdgru_kernel(
    const unsigned short* __restrict__ xhi, const unsigned short* __restrict__ xlo,
    const float* __restrict__ xraw, int use_xt,
    const unsigned short* __restrict__ Whi, const unsigned short* __restrict__ Wlo,
    const float* __restrict__ bias,
    float* __restrict__ out, unsigned int* __restrict__ stage, int use_stage,
    int* flags)
{
    extern __shared__ char smem[];
    unsigned short* As_hi = (unsigned short*)smem;               // 32*328*2 = 20992 B
    unsigned short* As_lo = (unsigned short*)(smem + 20992);     // 20992 B
    float*          Gx    = (float*)(smem + 41984);              // 32*385*4 = 49280 B
    float*          Gh    = (float*)(smem + 91264);              // 49280 B  (total 140544)

    const int blk = blockIdx.x;
    const int d   = blk / NC;
    const int c   = blk - d * NC;
    const int fy  = d & 1;
    const int fx  = (d >> 1) & 1;
    const int tid  = threadIdx.x;
    const int lane = tid & 63;
    const int wid  = tid >> 6;          // 0..7
    const int l15  = lane & 15;
    const int l4   = lane >> 4;
    const int j    = tid & (NHID - 1);  // epilogue hidden index
    const int bsub = tid >> 7;          // 0..3
    const int b0   = bsub * 8;

    const int xi = fx ? (62 - c) : c;
    const int X  = fx ? (63 - c) : c;
    const int Xp = fx ? (63 - (c - 1)) : (c - 1);

    // MFMA fragment lane offsets (A: row=l15, k=l4*8+i ; B: col=l15, k=l4*8+i)
    const int aoff = l15 * ASTR + l4 * 8;
    const unsigned short* wbh = Whi + ((size_t)d * NG + wid * 48 + l15) * NK + l4 * 8;
    const unsigned short* wbl = Wlo + ((size_t)d * NG + wid * 48 + l15) * NK + l4 * 8;

    const float bR = bias[d * NG + j];
    const float bZ = bias[d * NG + NHID + j];
    const float bN = bias[d * NG + 2 * NHID + j];

    // ---- prologue: zero h_up/h_left sections of both A planes; stage x row 0
    for (int e = tid; e < NB * 256; e += 512) {
        int bb = e >> 8, kk = e & 255;
        As_hi[bb * ASTR + 64 + kk] = 0;
        As_lo[bb * ASTR + 64 + kk] = 0;
    }
    {
        const int yi0 = fy ? 62 : 0;
        if (use_xt) {
            const size_t src = (size_t)(yi0 * NC + xi) * (NB * NIN) + tid * 4;
            us4 vh = *(const us4*)&xhi[src];
            us4 vl = *(const us4*)&xlo[src];
            const int e = tid * 4, bb = e >> 6, ii = e & 63;
            *(us4*)&As_hi[bb * ASTR + ii] = vh;
            *(us4*)&As_lo[bb * ASTR + ii] = vl;
        } else {
            for (int e = tid; e < NB * NIN; e += 512) {
                int bb = e >> 6, ii = e & 63;
                float v = xraw[((size_t)(bb * NIN + ii) * IMG + yi0) * IMG + xi];
                unsigned short hi, lo; split2(v, hi, lo);
                As_hi[bb * ASTR + ii] = hi;
                As_lo[bb * ASTR + ii] = lo;
            }
        }
    }
    float hprev[8];
#pragma unroll
    for (int q = 0; q < 8; ++q) hprev[q] = 0.0f;

    for (int r = 0; r < NC; ++r) {
        const int Y = fy ? (63 - r) : r;
        __syncthreads();                               // B1: As for row r ready

        fv4 accX[2][3], accH[2][3];
#pragma unroll
        for (int m = 0; m < 2; ++m)
#pragma unroll
            for (int t = 0; t < 3; ++t) {
                accX[m][t] = (fv4){0.f, 0.f, 0.f, 0.f};
                accH[m][t] = (fv4){0.f, 0.f, 0.f, 0.f};
            }

        // x part (k 0..63) -> accX ; prefetch next row's x
        KSTEP(0, accX); KSTEP(1, accX);
        us4 pxh, pxl; int have_px = 0;
        if (use_xt) {
            const int rn  = (r + 1 < NC) ? r + 1 : NC - 1;
            const int yin = fy ? (62 - rn) : rn;
            const size_t src = (size_t)(yin * NC + xi) * (NB * NIN) + tid * 4;
            pxh = *(const us4*)&xhi[src];
            pxl = *(const us4*)&xlo[src];
            have_px = 1;
        }
        // h_up part (k 64..191) -> accH
        KSTEP(2, accH); KSTEP(3, accH); KSTEP(4, accH); KSTEP(5, accH);

        // ---- acquire h_left from (d, c-1) row r ----
        float hl[8];
        if (c > 0) {
            if (tid == 0) {
                const int fidx = (d * NC + (c - 1)) * NC + r;
                int cnt = 0;
                while (__hip_atomic_load(&flags[fidx], __ATOMIC_RELAXED,
                                         __HIP_MEMORY_SCOPE_AGENT) == 0) {
                    __builtin_amdgcn_s_sleep(2);
                    if (++cnt > (1 << 22)) break;       // safety valve
                }
            }
            // B2 orders all threads after the poll; handoff loads below are
            // agent-scope (sc0/sc1) atomics that bypass L1/L2, so no cache
            // invalidate (buffer_inv) is needed -- data is read from the
            // coherence point the producer's vmcnt(0)-drained stores reached.
            __syncthreads();                            // B2
            if (use_stage) {
                const unsigned int* sp = stage +
                    ((size_t)(d * 2 + ((c - 1) & 1)) * NC + r) * (NB * NHID);
#pragma unroll
                for (int q = 0; q < 8; ++q) {
                    unsigned int p = __hip_atomic_load(sp + (b0 + q) * NHID + j,
                                                       __ATOMIC_RELAXED, __HIP_MEMORY_SCOPE_AGENT);
                    unsigned short hi = (unsigned short)(p >> 16);
                    unsigned short lo = (unsigned short)(p & 0xffffu);
                    hl[q] = bf16_f(hi) + bf16_f(lo);
                    As_hi[(b0 + q) * ASTR + 192 + j] = hi;
                    As_lo[(b0 + q) * ASTR + 192 + j] = lo;
                }
            } else {
                const float* pb = out + (size_t)j * (4 * IMG * IMG) + d * (IMG * IMG)
                                 + Y * IMG + Xp + (size_t)b0 * OUTB;
#pragma unroll
                for (int q = 0; q < 8; ++q) {
                    float v = __hip_atomic_load(pb + (size_t)q * OUTB,
                                                __ATOMIC_RELAXED, __HIP_MEMORY_SCOPE_AGENT);
                    hl[q] = v;
                    unsigned short hi, lo; split2(v, hi, lo);
                    As_hi[(b0 + q) * ASTR + 192 + j] = hi;
                    As_lo[(b0 + q) * ASTR + 192 + j] = lo;
                }
            }
            __syncthreads();                            // B3: h_left in LDS
        } else {
#pragma unroll
            for (int q = 0; q < 8; ++q) hl[q] = 0.0f;   // As h_left stays zero
        }

        // h_left part (k 192..319) -> accH
        KSTEP(6, accH); KSTEP(7, accH); KSTEP(8, accH); KSTEP(9, accH);

        // ---- regroup gates across waves via LDS ----
#pragma unroll
        for (int m = 0; m < 2; ++m)
#pragma unroll
            for (int t = 0; t < 3; ++t)
#pragma unroll
                for (int v = 0; v < 4; ++v) {
                    const int row = m * 16 + l4 * 4 + v;
                    const int g   = wid * 48 + t * 16 + l15;
                    Gx[row * GSTR + g] = accX[m][t][v];
                    Gh[row * GSTR + g] = accH[m][t][v];
                }
        __syncthreads();                                // B4: G ready

        // ---- gates + combine (fp32, exact reference form) ----
        unsigned int pu[8];
        unsigned short hhi[8], hlo[8];
#pragma unroll
        for (int q = 0; q < 8; ++q) {
            const int b = b0 + q;
            float gr = bR + Gx[b * GSTR + j]            + Gh[b * GSTR + j];
            float gz = bZ + Gx[b * GSTR + NHID + j]     + Gh[b * GSTR + NHID + j];
            float nx = bN + Gx[b * GSTR + 2 * NHID + j];
            float nh =      Gh[b * GSTR + 2 * NHID + j];
            float rg = sigmoidf_(gr);
            float zg = sigmoidf_(gz);
            float ng = tanhf_(fmaf(rg, nh, nx));
            float h  = (1.0f - zg) * ng + zg * 0.5f * (hprev[q] + hl[q]);
            hprev[q] = h;
            split2(h, hhi[q], hlo[q]);
            pu[q] = ((unsigned int)hhi[q] << 16) | hlo[q];
        }

        // ---- publish ----
        float* ob = out + (size_t)j * (4 * IMG * IMG) + d * (IMG * IMG)
                   + Y * IMG + X + (size_t)b0 * OUTB;
        if (use_stage) {
            if (c < NC - 1) {
                unsigned int* sw = stage +
                    ((size_t)(d * 2 + (c & 1)) * NC + r) * (NB * NHID) + b0 * NHID + j;
#pragma unroll
                for (int q = 0; q < 8; ++q)
                    __hip_atomic_store(sw + q * NHID, pu[q], __ATOMIC_RELAXED,
                                       __HIP_MEMORY_SCOPE_AGENT);
                // Drain this wave's stage stores to the coherence point.
                // (sc0/sc1 stores bypass L2 -> no buffer_wbl2 needed.)
                asm volatile("s_waitcnt vmcnt(0)" ::: "memory");
            }
            __syncthreads();                            // B5
            if (c < NC - 1 && tid == 0)
                __hip_atomic_store(&flags[(d * NC + c) * NC + r], 1,
                                   __ATOMIC_RELAXED, __HIP_MEMORY_SCOPE_AGENT);
#pragma unroll
            for (int q = 0; q < 8; ++q)
                ob[(size_t)q * OUTB] = hprev[q];        // off critical chain
        } else {
            // out IS the handoff surface
#pragma unroll
            for (int q = 0; q < 8; ++q)
                __hip_atomic_store(ob + (size_t)q * OUTB, hprev[q],
                                   __ATOMIC_RELAXED, __HIP_MEMORY_SCOPE_AGENT);
            if (c < NC - 1)
                asm volatile("s_waitcnt vmcnt(0)" ::: "memory");
            __syncthreads();                            // B5
            if (c < NC - 1 && tid == 0)
                __hip_atomic_store(&flags[(d * NC + c) * NC + r], 1,
                                   __ATOMIC_RELAXED, __HIP_MEMORY_SCOPE_AGENT);
        }

        // ---- write next row's As: h_up (from h) + x (prefetched) ----
#pragma unroll
        for (int q = 0; q < 8; ++q) {
            As_hi[(b0 + q) * ASTR + 64 + j] = hhi[q];
            As_lo[(b0 + q) * ASTR + 64 + j] = hlo[q];
        }
        if (have_px) {
            const int e = tid * 4, bb = e >> 6, ii = e & 63;
            *(us4*)&As_hi[bb * ASTR + ii] = pxh;
            *(us4*)&As_lo[bb * ASTR + ii] = pxl;
        } else if (r + 1 < NC) {
            const int yin = fy ? (62 - (r + 1)) : (r + 1);
            for (int e = tid; e < NB * NIN; e += 512) {
                int bb = e >> 6, ii = e & 63;
                float v = xraw[((size_t)(bb * NIN + ii) * IMG + yin) * IMG + xi];
                unsigned short hi, lo; split2(v, hi, lo);
                As_hi[bb * ASTR + ii] = hi;
                As_lo[bb * ASTR + ii] = lo;
            }
        }
    }
}

extern "C" void kernel_launch(void* const* d_in, const int* in_sizes, int n_in,
                              void* d_out, int out_size, void* d_ws, size_t ws_size,
                              hipStream_t stream) {
    const float* x    = (const float*)d_in[0];
    const float* Wx   = (const float*)d_in[1];
    const float* Wh   = (const float*)d_in[2];
    const float* Wh2  = (const float*)d_in[3];
    const float* bias = (const float*)d_in[4];
    float* out = (float*)d_out;

    // workspace layout
    const size_t FLAGS_BYTES = 65536;
    const size_t WHI_OFF  = FLAGS_BYTES;
    const size_t WSZ      = (size_t)4 * NG * NK * 2;
    const size_t WLO_OFF  = WHI_OFF + WSZ;
    const size_t XHI_OFF  = WLO_OFF + WSZ;
    const size_t XSZ      = (size_t)NC * NC * NB * NIN * 2;
    const size_t XLO_OFF  = XHI_OFF + XSZ;
    const size_t STG_OFF  = XLO_OFF + XSZ;                      // parity-ring stage
    const size_t STG_SZ   = (size_t)4 * 2 * NC * NB * NHID * 4; // 8,257,536
    const size_t SMEM     = 140544;

    int*            flags = (int*)d_ws;
    unsigned short* whi   = (unsigned short*)((char*)d_ws + WHI_OFF);
    unsigned short* wlo   = (unsigned short*)((char*)d_ws + WLO_OFF);
    unsigned short* xhi   = (unsigned short*)((char*)d_ws + XHI_OFF);
    unsigned short* xlo   = (unsigned short*)((char*)d_ws + XLO_OFF);
    unsigned int*   stage = (unsigned int*)((char*)d_ws + STG_OFF);
    const int use_xt    = ws_size >= XLO_OFF + XSZ;
    const int use_stage = ws_size >= STG_OFF + STG_SZ;

    (void)hipFuncSetAttribute((const void*)mdgru_kernel,
                              hipFuncAttributeMaxDynamicSharedMemorySize, (int)SMEM);

    size_t mset = ws_size < FLAGS_BYTES ? ws_size : FLAGS_BYTES;
    hipMemsetAsync(d_ws, 0, mset, stream);               // flags start at 0

    {
        const int total = 4 * NG * NK;
        wsplit_kernel<<<(total + 255) / 256, 256, 0, stream>>>(Wx, Wh, Wh2, whi, wlo);
    }
    if (use_xt) {
        const int total = NC * NC * NB * NIN;
        xsplit_kernel<<<(total + 255) / 256, 256, 0, stream>>>(x, xhi, xlo);
    }
    fill_kernel<<<(NB * NHID * 4 * 2 * 64 + 255) / 256, 256, 0, stream>>>(out);
    mdgru_kernel<<<4 * NC, 512, SMEM, stream>>>(xhi, xlo, x, use_xt, whi, wlo, bias,
                                                out, stage, use_stage, flags);
}

// Round 9
// 4047.210 us; speedup vs baseline: 2.0716x; 1.3853x over previous
//
#include <hip/hip_runtime.h>
#include <stdint.h>

// MD-GRU 2D, 4 directions. B=32, IN=64, H=W=64 (63x63 cells), HID=128.
// Persistent wavefront pipeline (one 512-thread WG per direction*column),
// flag h_left handoff via agent-scope (sc0/sc1, L2-bypassing) atomics.
// The wavefront kernel never touches `out` (whose [b][j][d][Y][X] layout
// caused ~5 GB of RFO line amplification = round-6's 5.2 ms). Cells go fp32
// into a dense hbuf[d][c][r][bj] (coalesced, also the h_left handoff
// surface); a parallel unpack kernel does the layout transpose afterwards.
// Round-9 fix: unpack's bj loop now covers all 4096 (b,j) pairs (round-8
// covered 2048 -> half the batches stayed zero, absmax 0.82).

#define NB   32
#define NIN  64
#define NHID 128
#define NG   384
#define NC   63
#define IMG  64
#define NK   320           // 64 x | 128 h_up | 128 h_left
#define ASTR 328           // LDS A-plane row stride (ushorts), +8 pad
#define GSTR 385           // LDS G-plane row stride (floats), +1 pad
#define OUTB ((size_t)NHID * 4 * IMG * IMG)   // batch stride in out

typedef __attribute__((ext_vector_type(8))) short short8;
typedef __attribute__((ext_vector_type(4))) float fv4;
typedef __attribute__((ext_vector_type(4))) unsigned short us4;

__device__ __forceinline__ float sigmoidf_(float x) { return 1.0f / (1.0f + __expf(-x)); }
__device__ __forceinline__ float tanhf_(float x)    { return 1.0f - 2.0f / (__expf(2.0f * x) + 1.0f); }

__device__ __forceinline__ unsigned short bf16_rne(float f) {
    unsigned int u = __builtin_bit_cast(unsigned int, f);
    u += 0x7fffu + ((u >> 16) & 1u);
    return (unsigned short)(u >> 16);
}
__device__ __forceinline__ float bf16_f(unsigned short h) {
    return __builtin_bit_cast(float, ((unsigned int)h) << 16);
}
__device__ __forceinline__ void split2(float f, unsigned short& hi, unsigned short& lo) {
    hi = bf16_rne(f);
    lo = bf16_rne(f - bf16_f(hi));
}

// x (B,IN,64,64) -> hi/lo bf16 planes xT*[(y*63+xc)*2048 + b*64 + i]
// LDS tile transpose per (b, y): reads coalesced along xc, writes 128B runs.
__global__ __launch_bounds__(512) void xsplit_kernel(const float* __restrict__ x,
                                                     unsigned short* __restrict__ xhi,
                                                     unsigned short* __restrict__ xlo) {
    __shared__ float tile[64][65];
    const int blk = blockIdx.x;       // b*63 + y
    const int y = blk % 63;
    const int b = blk / 63;
    for (int e = threadIdx.x; e < 64 * 64; e += 512) {
        const int i = e >> 6, xc = e & 63;
        tile[i][xc] = x[((size_t)(b * NIN + i) * IMG + y) * IMG + xc];
    }
    __syncthreads();
    for (int e = threadIdx.x; e < 63 * 64; e += 512) {
        const int xc = e >> 6, i = e & 63;
        unsigned short hi, lo; split2(tile[i][xc], hi, lo);
        const size_t o = (size_t)(y * NC + xc) * (NB * NIN) + b * NIN + i;
        xhi[o] = hi; xlo[o] = lo;
    }
}

// [Wx;Wh;Wh2] -> K-major hi/lo planes W*[d][gate][k], k = 0..319
__global__ void wsplit_kernel(const float* __restrict__ Wx, const float* __restrict__ Wh,
                              const float* __restrict__ Wh2,
                              unsigned short* __restrict__ whi,
                              unsigned short* __restrict__ wlo) {
    int idx = blockIdx.x * 256 + threadIdx.x;
    if (idx >= 4 * NG * NK) return;
    int k = idx % NK;
    int g = (idx / NK) % NG;
    int d = idx / (NK * NG);
    float v;
    if (k < NIN)             v = Wx [((size_t)d * NIN  + k)                * NG + g];
    else if (k < NIN + NHID) v = Wh [((size_t)d * NHID + (k - NIN))        * NG + g];
    else                     v = Wh2[((size_t)d * NHID + (k - NIN - NHID)) * NG + g];
    unsigned short hi, lo; split2(v, hi, lo);
    whi[idx] = hi; wlo[idx] = lo;
}

// 1.0 border cells of each direction's map. out[b][j][d][Y][X].
__global__ void fill_kernel(float* __restrict__ out) {
    int idx  = blockIdx.x * 256 + threadIdx.x;
    int pos  = idx & 63;
    int line = (idx >> 6) & 1;
    int rest = idx >> 7;
    if (rest >= NB * NHID * 4) return;
    int d  = rest & 3;
    int fy = d & 1, fx = (d >> 1) & 1;
    int Y = line ? pos : (fy ? 0 : 63);
    int X = line ? (fx ? 0 : 63) : pos;
    out[(size_t)rest * (IMG * IMG) + Y * IMG + X] = 1.0f;
}

// hbuf[d][c][r][bj] -> out[b][j][d][Y][X]. Block = (d, r, c-tile of 16).
// Reads coalesced across bj; each thread fills (most of) one 64B out line.
// Plain loads: unpack runs in a separate launch after mdgru completes, so
// the kernel-boundary acquire makes hbuf visible without sc0/sc1 bypass.
__global__ __launch_bounds__(512) void unpack_kernel(const float* __restrict__ hbuf,
                                                     float* __restrict__ out) {
    const int blk = blockIdx.x;            // ((d*NC)+r)*4 + ct
    const int ct  = blk & 3;
    const int r   = (blk >> 2) % NC;
    const int d   = blk / (4 * NC);
    const int fy  = d & 1, fx = (d >> 1) & 1;
    const int Y   = fy ? 63 - r : r;
    const int c0  = ct * 16;
    const int nc  = (c0 + 16 <= NC) ? 16 : NC - c0;
    for (int s = 0; s < 8; ++s) {              // 8*512 = 4096 = NB*NHID
        const int bj = threadIdx.x + s * 512;
        const int b = bj >> 7, j = bj & 127;
        float* o = out + ((((size_t)b * NHID + j) * 4 + d) * IMG + Y) * IMG;
#pragma unroll 4
        for (int u = 0; u < nc; ++u) {
            const int c = c0 + u;
            float v = hbuf[((size_t)(d * NC + c) * NC + r) * (NB * NHID) + bj];
            const int X = fx ? 63 - c : c;
            o[X] = v;
        }
    }
}

// One K=32 MFMA step for both M-tiles and this wave's 3 N-tiles into ACC.
// Split products: Ahi*Bhi + Ahi*Blo + Alo*Bhi (Alo*Blo ~2^-18, dropped).
#define KSTEP(S, ACC)                                                                 \
    do {                                                                              \
        short8 a0h = *(const short8*)&As_hi[aoff + (S) * 32];                         \
        short8 a0l = *(const short8*)&As_lo[aoff + (S) * 32];                         \
        short8 a1h = *(const short8*)&As_hi[aoff + 16 * ASTR + (S) * 32];             \
        short8 a1l = *(const short8*)&As_lo[aoff + 16 * ASTR + (S) * 32];             \
        _Pragma("unroll")                                                             \
        for (int t = 0; t < 3; ++t) {                                                 \
            short8 bh = *(const short8*)&wbh[(size_t)t * 16 * NK + (S) * 32];         \
            short8 bl = *(const short8*)&wbl[(size_t)t * 16 * NK + (S) * 32];         \
            ACC[0][t] = __builtin_amdgcn_mfma_f32_16x16x32_bf16(a0h, bh, ACC[0][t], 0, 0, 0); \
            ACC[0][t] = __builtin_amdgcn_mfma_f32_16x16x32_bf16(a0h, bl, ACC[0][t], 0, 0, 0); \
            ACC[0][t] = __builtin_amdgcn_mfma_f32_16x16x32_bf16(a0l, bh, ACC[0][t], 0, 0, 0); \
            ACC[1][t] = __builtin_amdgcn_mfma_f32_16x16x32_bf16(a1h, bh, ACC[1][t], 0, 0, 0); \
            ACC[1][t] = __builtin_amdgcn_mfma_f32_16x16x32_bf16(a1h, bl, ACC[1][t], 0, 0, 0); \
            ACC[1][t] = __builtin_amdgcn_mfma_f32_16x16x32_bf16(a1l, bh, ACC[1][t], 0, 0, 0); \
        }                                                                             \
    } while (0)

__global__ __launch_bounds__(512) void mdgru_kernel(
    const unsigned short* __restrict__ xhi, const unsigned short* __restrict__ xlo,
    const float* __restrict__ xraw, int use_xt,
    const unsigned short* __restrict__ Whi, const unsigned short* __restrict__ Wlo,
    const float* __restrict__ bias,
    float* __restrict__ out, float* __restrict__ hbuf, int use_big,
    int* flags)
{
    extern __shared__ char smem[];
    unsigned short* As_hi = (unsigned short*)smem;               // 32*328*2 = 20992 B
    unsigned short* As_lo = (unsigned short*)(smem + 20992);     // 20992 B
    float*          Gx    = (float*)(smem + 41984);              // 32*385*4 = 49280 B
    float*          Gh    = (float*)(smem + 91264);              // 49280 B  (total 140544)

    const int blk = blockIdx.x;
    const int d   = blk / NC;
    const int c   = blk - d * NC;
    const int fy  = d & 1;
    const int fx  = (d >> 1) & 1;
    const int tid  = threadIdx.x;
    const int lane = tid & 63;
    const int wid  = tid >> 6;          // 0..7
    const int l15  = lane & 15;
    const int l4   = lane >> 4;
    const int j    = tid & (NHID - 1);  // epilogue hidden index
    const int bsub = tid >> 7;          // 0..3
    const int b0   = bsub * 8;

    const int xi = fx ? (62 - c) : c;
    const int X  = fx ? (63 - c) : c;
    const int Xp = fx ? (63 - (c - 1)) : (c - 1);

    // MFMA fragment lane offsets (A: row=l15, k=l4*8+i ; B: col=l15, k=l4*8+i)
    const int aoff = l15 * ASTR + l4 * 8;
    const unsigned short* wbh = Whi + ((size_t)d * NG + wid * 48 + l15) * NK + l4 * 8;
    const unsigned short* wbl = Wlo + ((size_t)d * NG + wid * 48 + l15) * NK + l4 * 8;

    const float bR = bias[d * NG + j];
    const float bZ = bias[d * NG + NHID + j];
    const float bN = bias[d * NG + 2 * NHID + j];

    // ---- prologue: zero h_up/h_left sections of both A planes; stage x row 0
    for (int e = tid; e < NB * 256; e += 512) {
        int bb = e >> 8, kk = e & 255;
        As_hi[bb * ASTR + 64 + kk] = 0;
        As_lo[bb * ASTR + 64 + kk] = 0;
    }
    {
        const int yi0 = fy ? 62 : 0;
        if (use_xt) {
            const size_t src = (size_t)(yi0 * NC + xi) * (NB * NIN) + tid * 4;
            us4 vh = *(const us4*)&xhi[src];
            us4 vl = *(const us4*)&xlo[src];
            const int e = tid * 4, bb = e >> 6, ii = e & 63;
            *(us4*)&As_hi[bb * ASTR + ii] = vh;
            *(us4*)&As_lo[bb * ASTR + ii] = vl;
        } else {
            for (int e = tid; e < NB * NIN; e += 512) {
                int bb = e >> 6, ii = e & 63;
                float v = xraw[((size_t)(bb * NIN + ii) * IMG + yi0) * IMG + xi];
                unsigned short hi, lo; split2(v, hi, lo);
                As_hi[bb * ASTR + ii] = hi;
                As_lo[bb * ASTR + ii] = lo;
            }
        }
    }
    float hprev[8];
#pragma unroll
    for (int q = 0; q < 8; ++q) hprev[q] = 0.0f;

    for (int r = 0; r < NC; ++r) {
        const int Y = fy ? (63 - r) : r;
        __syncthreads();                               // B1: As for row r ready

        fv4 accX[2][3], accH[2][3];
#pragma unroll
        for (int m = 0; m < 2; ++m)
#pragma unroll
            for (int t = 0; t < 3; ++t) {
                accX[m][t] = (fv4){0.f, 0.f, 0.f, 0.f};
                accH[m][t] = (fv4){0.f, 0.f, 0.f, 0.f};
            }

        // x part (k 0..63) -> accX ; prefetch next row's x
        KSTEP(0, accX); KSTEP(1, accX);
        us4 pxh, pxl; int have_px = 0;
        if (use_xt) {
            const int rn  = (r + 1 < NC) ? r + 1 : NC - 1;
            const int yin = fy ? (62 - rn) : rn;
            const size_t src = (size_t)(yin * NC + xi) * (NB * NIN) + tid * 4;
            pxh = *(const us4*)&xhi[src];
            pxl = *(const us4*)&xlo[src];
            have_px = 1;
        }
        // h_up part (k 64..191) -> accH
        KSTEP(2, accH); KSTEP(3, accH); KSTEP(4, accH); KSTEP(5, accH);

        // ---- acquire h_left from (d, c-1) row r ----
        float hl[8];
        if (c > 0) {
            if (tid == 0) {
                const int fidx = (d * NC + (c - 1)) * NC + r;
                int cnt = 0;
                while (__hip_atomic_load(&flags[fidx], __ATOMIC_RELAXED,
                                         __HIP_MEMORY_SCOPE_AGENT) == 0) {
                    __builtin_amdgcn_s_sleep(2);
                    if (++cnt > (1 << 22)) break;       // safety valve
                }
            }
            // B2 orders all threads after the poll; handoff loads below are
            // agent-scope (sc0/sc1) atomics bypassing the non-coherent L2.
            __syncthreads();                            // B2
            if (use_big) {
                const float* sp = hbuf +
                    ((size_t)(d * NC + (c - 1)) * NC + r) * (NB * NHID);
#pragma unroll
                for (int q = 0; q < 8; ++q) {
                    float v = __hip_atomic_load(sp + (b0 + q) * NHID + j,
                                                __ATOMIC_RELAXED, __HIP_MEMORY_SCOPE_AGENT);
                    hl[q] = v;
                    unsigned short hi, lo; split2(v, hi, lo);
                    As_hi[(b0 + q) * ASTR + 192 + j] = hi;
                    As_lo[(b0 + q) * ASTR + 192 + j] = lo;
                }
            } else {
                const float* pb = out + (size_t)j * (4 * IMG * IMG) + d * (IMG * IMG)
                                 + Y * IMG + Xp + (size_t)b0 * OUTB;
#pragma unroll
                for (int q = 0; q < 8; ++q) {
                    float v = __hip_atomic_load(pb + (size_t)q * OUTB,
                                                __ATOMIC_RELAXED, __HIP_MEMORY_SCOPE_AGENT);
                    hl[q] = v;
                    unsigned short hi, lo; split2(v, hi, lo);
                    As_hi[(b0 + q) * ASTR + 192 + j] = hi;
                    As_lo[(b0 + q) * ASTR + 192 + j] = lo;
                }
            }
            __syncthreads();                            // B3: h_left in LDS
        } else {
#pragma unroll
            for (int q = 0; q < 8; ++q) hl[q] = 0.0f;   // As h_left stays zero
        }

        // h_left part (k 192..319) -> accH
        KSTEP(6, accH); KSTEP(7, accH); KSTEP(8, accH); KSTEP(9, accH);

        // ---- regroup gates across waves via LDS ----
#pragma unroll
        for (int m = 0; m < 2; ++m)
#pragma unroll
            for (int t = 0; t < 3; ++t)
#pragma unroll
                for (int v = 0; v < 4; ++v) {
                    const int row = m * 16 + l4 * 4 + v;
                    const int g   = wid * 48 + t * 16 + l15;
                    Gx[row * GSTR + g] = accX[m][t][v];
                    Gh[row * GSTR + g] = accH[m][t][v];
                }
        __syncthreads();                                // B4: G ready

        // ---- gates + combine (fp32, exact reference form) ----
        unsigned short hhi[8], hlo[8];
#pragma unroll
        for (int q = 0; q < 8; ++q) {
            const int b = b0 + q;
            float gr = bR + Gx[b * GSTR + j]            + Gh[b * GSTR + j];
            float gz = bZ + Gx[b * GSTR + NHID + j]     + Gh[b * GSTR + NHID + j];
            float nx = bN + Gx[b * GSTR + 2 * NHID + j];
            float nh =      Gh[b * GSTR + 2 * NHID + j];
            float rg = sigmoidf_(gr);
            float zg = sigmoidf_(gz);
            float ng = tanhf_(fmaf(rg, nh, nx));
            float h  = (1.0f - zg) * ng + zg * 0.5f * (hprev[q] + hl[q]);
            hprev[q] = h;
            split2(h, hhi[q], hlo[q]);
        }

        // ---- publish ----
        if (use_big) {
            // coalesced fp32 stores into hbuf (also the handoff surface)
            float* hw = hbuf + ((size_t)(d * NC + c) * NC + r) * (NB * NHID)
                       + b0 * NHID + j;
#pragma unroll
            for (int q = 0; q < 8; ++q)
                __hip_atomic_store(hw + q * NHID, hprev[q], __ATOMIC_RELAXED,
                                   __HIP_MEMORY_SCOPE_AGENT);
            if (c < NC - 1)
                asm volatile("s_waitcnt vmcnt(0)" ::: "memory");
            __syncthreads();                            // B5
            if (c < NC - 1 && tid == 0)
                __hip_atomic_store(&flags[(d * NC + c) * NC + r], 1,
                                   __ATOMIC_RELAXED, __HIP_MEMORY_SCOPE_AGENT);
        } else {
            // out IS the handoff surface (fallback when ws too small)
            float* ob = out + (size_t)j * (4 * IMG * IMG) + d * (IMG * IMG)
                       + Y * IMG + X + (size_t)b0 * OUTB;
#pragma unroll
            for (int q = 0; q < 8; ++q)
                __hip_atomic_store(ob + (size_t)q * OUTB, hprev[q],
                                   __ATOMIC_RELAXED, __HIP_MEMORY_SCOPE_AGENT);
            if (c < NC - 1)
                asm volatile("s_waitcnt vmcnt(0)" ::: "memory");
            __syncthreads();                            // B5
            if (c < NC - 1 && tid == 0)
                __hip_atomic_store(&flags[(d * NC + c) * NC + r], 1,
                                   __ATOMIC_RELAXED, __HIP_MEMORY_SCOPE_AGENT);
        }

        // ---- write next row's As: h_up (from h) + x (prefetched) ----
#pragma unroll
        for (int q = 0; q < 8; ++q) {
            As_hi[(b0 + q) * ASTR + 64 + j] = hhi[q];
            As_lo[(b0 + q) * ASTR + 64 + j] = hlo[q];
        }
        if (have_px) {
            const int e = tid * 4, bb = e >> 6, ii = e & 63;
            *(us4*)&As_hi[bb * ASTR + ii] = pxh;
            *(us4*)&As_lo[bb * ASTR + ii] = pxl;
        } else if (r + 1 < NC) {
            const int yin = fy ? (62 - (r + 1)) : (r + 1);
            for (int e = tid; e < NB * NIN; e += 512) {
                int bb = e >> 6, ii = e & 63;
                float v = xraw[((size_t)(bb * NIN + ii) * IMG + yin) * IMG + xi];
                unsigned short hi, lo; split2(v, hi, lo);
                As_hi[bb * ASTR + ii] = hi;
                As_lo[bb * ASTR + ii] = lo;
            }
        }
    }
}

extern "C" void kernel_launch(void* const* d_in, const int* in_sizes, int n_in,
                              void* d_out, int out_size, void* d_ws, size_t ws_size,
                              hipStream_t stream) {
    const float* x    = (const float*)d_in[0];
    const float* Wx   = (const float*)d_in[1];
    const float* Wh   = (const float*)d_in[2];
    const float* Wh2  = (const float*)d_in[3];
    const float* bias = (const float*)d_in[4];
    float* out = (float*)d_out;

    // workspace layout
    const size_t FLAGS_BYTES = 65536;
    const size_t WHI_OFF  = FLAGS_BYTES;
    const size_t WSZ      = (size_t)4 * NG * NK * 2;             // 983,040
    const size_t WLO_OFF  = WHI_OFF + WSZ;
    const size_t XHI_OFF  = WLO_OFF + WSZ;
    const size_t XSZ      = (size_t)NC * NC * NB * NIN * 2;      // 16,257,024
    const size_t XLO_OFF  = XHI_OFF + XSZ;
    const size_t HB_OFF   = XLO_OFF + XSZ;                       // 34,545,664
    const size_t HB_SZ    = (size_t)4 * NC * NC * NB * NHID * 4; // 260,112,384
    const size_t SMEM     = 140544;

    int*            flags = (int*)d_ws;
    unsigned short* whi   = (unsigned short*)((char*)d_ws + WHI_OFF);
    unsigned short* wlo   = (unsigned short*)((char*)d_ws + WLO_OFF);
    unsigned short* xhi   = (unsigned short*)((char*)d_ws + XHI_OFF);
    unsigned short* xlo   = (unsigned short*)((char*)d_ws + XLO_OFF);
    float*          hbuf  = (float*)((char*)d_ws + HB_OFF);
    const int use_xt  = ws_size >= XLO_OFF + XSZ;
    const int use_big = ws_size >= HB_OFF + HB_SZ;

    (void)hipFuncSetAttribute((const void*)mdgru_kernel,
                              hipFuncAttributeMaxDynamicSharedMemorySize, (int)SMEM);

    size_t mset = ws_size < FLAGS_BYTES ? ws_size : FLAGS_BYTES;
    hipMemsetAsync(d_ws, 0, mset, stream);               // flags start at 0

    {
        const int total = 4 * NG * NK;
        wsplit_kernel<<<(total + 255) / 256, 256, 0, stream>>>(Wx, Wh, Wh2, whi, wlo);
    }
    if (use_xt) {
        xsplit_kernel<<<NB * 63, 512, 0, stream>>>(x, xhi, xlo);
    }
    fill_kernel<<<(NB * NHID * 4 * 2 * 64 + 255) / 256, 256, 0, stream>>>(out);
    mdgru_kernel<<<4 * NC, 512, SMEM, stream>>>(xhi, xlo, x, use_xt, whi, wlo, bias,
                                                out, hbuf, use_big, flags);
    if (use_big) {
        unpack_kernel<<<4 * NC * 4, 512, 0, stream>>>(hbuf, out);
    }
}